// Round 8
// baseline (320.759 us; speedup 1.0000x reference)
//
#include <hip/hip_runtime.h>
#include <hip/hip_fp16.h>

#define N_NODES 50000
#define N_HID   64
#define N_LAYER 4
#define N_CLASS 40
#define N_EDGES 800000

#define BSHIFT 8
#define BSIZE  256                                      // nodes per bucket
#define NBUCK  ((N_NODES + BSIZE - 1) / BSIZE)          // 196
#define BPAD   16                                       // bucket-cursor stride (64B)
#define EPT    16                                       // edges per thread (hist/bucket)
#define BKCHUNK (256 * EPT)                             // 4096 edges per block
#define NBBLK  ((N_EDGES + BKCHUNK - 1) / BKCHUNK)      // 196

// ---------------- build: bucket histogram (LDS-aggregated) ----------------

__global__ void k_hist(const int* __restrict__ dst, int* __restrict__ bktot) {
    __shared__ int lh[NBUCK];
    int t = threadIdx.x;
    for (int i = t; i < NBUCK; i += 256) lh[i] = 0;
    __syncthreads();
    int base = blockIdx.x * BKCHUNK;
#pragma unroll
    for (int i = 0; i < EPT; i++) {
        int e = base + i * 256 + t;
        if (e < N_EDGES) atomicAdd(&lh[dst[e] >> BSHIFT], 1);
    }
    __syncthreads();
    for (int i = t; i < NBUCK; i += 256) {
        int v = lh[i];
        if (v) atomicAdd(&bktot[i], v);
    }
}

// single block: exclusive scan of 196 bucket totals -> bbase; init bcur
__global__ void k_scanb(const int* __restrict__ bktot, int* __restrict__ bbase,
                        int* __restrict__ bcur) {
    __shared__ int tmp[256];
    int t = threadIdx.x;
    int v = (t < NBUCK) ? bktot[t] : 0;
    tmp[t] = v;
    __syncthreads();
    for (int off = 1; off < 256; off <<= 1) {
        int u = (t >= off) ? tmp[t - off] : 0;
        __syncthreads();
        tmp[t] += u;
        __syncthreads();
    }
    int excl = tmp[t] - v;
    if (t < NBUCK) { bbase[t] = excl; bcur[t * BPAD] = excl; }
    if (t == NBUCK - 1) bbase[NBUCK] = excl + v;   // = N_EDGES
}

// block-binned append of packed (dst<<16)|src into dst-bucket windows
__global__ void k_bucket(const int* __restrict__ src, const int* __restrict__ dst,
                         int* __restrict__ bcur, unsigned int* __restrict__ stag) {
    __shared__ int lhist[NBUCK];
    __shared__ int gbase[NBUCK];
    int t = threadIdx.x;
    for (int i = t; i < NBUCK; i += 256) lhist[i] = 0;
    __syncthreads();

    int base = blockIdx.x * BKCHUNK;
    unsigned int rec[EPT];
    int br[EPT];
#pragma unroll
    for (int i = 0; i < EPT; i++) {
        int e = base + i * 256 + t;      // coalesced
        if (e < N_EDGES) {
            int d = dst[e], s = src[e];
            int b = d >> BSHIFT;
            int r = atomicAdd(&lhist[b], 1);   // in-block rank within bucket
            rec[i] = ((unsigned int)d << 16) | (unsigned int)s;
            br[i]  = (b << 16) | r;            // r < 4096
        } else {
            br[i] = -1;
        }
    }
    __syncthreads();
    for (int i = t; i < NBUCK; i += 256) {
        int c = lhist[i];
        gbase[i] = c ? atomicAdd(&bcur[i * BPAD], c) : 0;
    }
    __syncthreads();
#pragma unroll
    for (int i = 0; i < EPT; i++) {
        if (br[i] >= 0) {
            int b = br[i] >> 16, r = br[i] & 0xffff;
            stag[gbase[b] + r] = rec[i];
        }
    }
}

// per-bucket: LDS count + scan over the bucket's staging window ->
// cnt / cursor / dinv per node, then scatter src into exact CSR slots.
__global__ void k_csr2(const unsigned int* __restrict__ stag, const int* __restrict__ bbase,
                       int* __restrict__ cnt, int* __restrict__ cursor,
                       float* __restrict__ dinv, unsigned short* __restrict__ csr16) {
    __shared__ int lcnt[BSIZE], ltmp[BSIZE], lcur[BSIZE];
    int b = blockIdx.x, t = threadIdx.x;
    int bstart = bbase[b], bend = bbase[b + 1];
    lcnt[t] = 0;
    __syncthreads();
    for (int i = bstart + t; i < bend; i += 256)
        atomicAdd(&lcnt[(stag[i] >> 16) & (BSIZE - 1)], 1);
    __syncthreads();
    int v = lcnt[t];
    ltmp[t] = v;
    __syncthreads();
    for (int off = 1; off < 256; off <<= 1) {
        int u = (t >= off) ? ltmp[t - off] : 0;
        __syncthreads();
        ltmp[t] += u;
        __syncthreads();
    }
    int cur = bstart + ltmp[t] - v;      // node's CSR row start
    lcur[t] = cur;
    int node = (b << BSHIFT) + t;
    if (node < N_NODES) {
        cnt[node]    = v;
        cursor[node] = cur;
        dinv[node]   = rsqrtf((float)(v + 1));
    }
    __syncthreads();
    for (int i = bstart + t; i < bend; i += 256) {
        unsigned int rec = stag[i];
        int p = atomicAdd(&lcur[(rec >> 16) & (BSIZE - 1)], 1);
        csr16[p] = (unsigned short)rec;
    }
}

// ---------------- layer-0 GEMM: hd = half((x @ W0) * dinv) ----------------
// 1024 threads = 16 waves; wave w owns node w. No cross-wave LDS sharing.

__global__ __launch_bounds__(1024) void k_gemm0(const float* __restrict__ A,
                                                const float* __restrict__ W,
                                                const float* __restrict__ dinv,
                                                __half* __restrict__ hd) {
    __shared__ float As[16][128];
    int tid = threadIdx.x;
    int w = tid >> 6, j = tid & 63;
    int n = blockIdx.x * 16 + w;

    ((float2*)&As[w][0])[j] = ((const float2*)(A + (size_t)n * 128))[j];  // own-wave stage
    __builtin_amdgcn_wave_barrier();      // same-wave DS ops execute in order

    float acc = 0.f;
#pragma unroll
    for (int k = 0; k < 128; k += 4) {
        float4 a = *(const float4*)&As[w][k];       // wave-uniform broadcast
        acc = fmaf(a.x, W[(k + 0) * 64 + j], acc);
        acc = fmaf(a.y, W[(k + 1) * 64 + j], acc);
        acc = fmaf(a.z, W[(k + 2) * 64 + j], acc);
        acc = fmaf(a.w, W[(k + 3) * 64 + j], acc);
    }
    hd[(size_t)n * 64 + j] = __float2half(acc * dinv[n]);
}

// ---------------- agg for one node by one wave ----------------
// returns (hw-combined) neighbor sum for feature pair j

__device__ __forceinline__ float2 agg_node(const __half2* __restrict__ hd,
                                           const int* __restrict__ cnt,
                                           const int* __restrict__ cursor,
                                           const unsigned short* __restrict__ csr16,
                                           int n, int j, int hw) {
    int k   = cursor[n];
    int end = k + cnt[n];
    float sx = 0.f, sy = 0.f;
    for (; k + 8 <= end; k += 8) {       // 4 gathers in flight per lane-half
        int s0 = csr16[k + hw],     s1 = csr16[k + 2 + hw];
        int s2 = csr16[k + 4 + hw], s3 = csr16[k + 6 + hw];
        float2 v0 = __half22float2(hd[(size_t)s0 * 32 + j]);
        float2 v1 = __half22float2(hd[(size_t)s1 * 32 + j]);
        float2 v2 = __half22float2(hd[(size_t)s2 * 32 + j]);
        float2 v3 = __half22float2(hd[(size_t)s3 * 32 + j]);
        sx += (v0.x + v1.x) + (v2.x + v3.x);
        sy += (v0.y + v1.y) + (v2.y + v3.y);
    }
    if (k + 4 <= end) {
        int s0 = csr16[k + hw], s1 = csr16[k + 2 + hw];
        float2 v0 = __half22float2(hd[(size_t)s0 * 32 + j]);
        float2 v1 = __half22float2(hd[(size_t)s1 * 32 + j]);
        sx += v0.x + v1.x;
        sy += v0.y + v1.y;
        k += 4;
    }
    if (k + 2 <= end) {
        int s0 = csr16[k + hw];
        float2 v0 = __half22float2(hd[(size_t)s0 * 32 + j]);
        sx += v0.x; sy += v0.y;
        k += 2;
    }
    if (hw == 0 && k < end) {
        int s0 = csr16[k];
        float2 v0 = __half22float2(hd[(size_t)s0 * 32 + j]);
        sx += v0.x; sy += v0.y;
    }
    sx += __shfl_xor(sx, 32);
    sy += __shfl_xor(sy, 32);
    return make_float2(sx, sy);
}

// ---------------- fused: agg(layer l) + gemm(layer l+1) ----------------

__global__ __launch_bounds__(1024) void k_fused(const __half2* __restrict__ hd_in,
                                                const float* __restrict__ b,
                                                const float* __restrict__ dinv,
                                                const int* __restrict__ cnt,
                                                const int* __restrict__ cursor,
                                                const unsigned short* __restrict__ csr16,
                                                const float* __restrict__ W,
                                                __half* __restrict__ hs_out,
                                                __half* __restrict__ hd_out) {
    __shared__ float As[16][64];
    int tid = threadIdx.x;
    int w = tid >> 6, lane = tid & 63;
    int j = lane & 31, hw = lane >> 5;
    int n = blockIdx.x * 16 + w;

    float2 s = agg_node(hd_in, cnt, cursor, csr16, n, j, hw);
    if (hw == 0) {
        float dv = dinv[n];
        float2 sv = __half22float2(hd_in[(size_t)n * 32 + j]);   // self row
        float ox = fmaxf(fmaf(s.x + sv.x, dv, b[2 * j]), 0.f);
        float oy = fmaxf(fmaf(s.y + sv.y, dv, b[2 * j + 1]), 0.f);
        ((float2*)&As[w][0])[j] = make_float2(ox, oy);
        ((__half2*)hs_out)[(size_t)n * 32 + j] =
            __halves2half2(__float2half(ox), __float2half(oy));
    }
    __builtin_amdgcn_wave_barrier();      // own-wave LDS handoff (in-order DS)

    float acc = 0.f;
#pragma unroll
    for (int k = 0; k < 64; k += 4) {
        float4 a = *(const float4*)&As[w][k];
        acc = fmaf(a.x, W[(k + 0) * 64 + lane], acc);
        acc = fmaf(a.y, W[(k + 1) * 64 + lane], acc);
        acc = fmaf(a.z, W[(k + 2) * 64 + lane], acc);
        acc = fmaf(a.w, W[(k + 3) * 64 + lane], acc);
    }
    hd_out[(size_t)n * 64 + lane] = __float2half(acc * dinv[n]);
}

// ---------------- last: agg(l3) + layer-attention + projection ----------------

__global__ __launch_bounds__(1024) void k_last(const __half2* __restrict__ hd_in,
                                               const float* __restrict__ b,
                                               const float* __restrict__ dinv,
                                               const int* __restrict__ cnt,
                                               const int* __restrict__ cursor,
                                               const unsigned short* __restrict__ csr16,
                                               const __half* __restrict__ hs16,
                                               const float* __restrict__ Wout,
                                               const float* __restrict__ bout,
                                               float* __restrict__ out) {
    __shared__ float As[16][64];
    int tid = threadIdx.x;
    int w = tid >> 6, lane = tid & 63;
    int j = lane & 31, hw = lane >> 5;
    int n = blockIdx.x * 16 + w;

    float2 s = agg_node(hd_in, cnt, cursor, csr16, n, j, hw);
    if (hw == 0) {
        float dv = dinv[n];
        float2 sv = __half22float2(hd_in[(size_t)n * 32 + j]);
        float ox = fmaxf(fmaf(s.x + sv.x, dv, b[2 * j]), 0.f);
        float oy = fmaxf(fmaf(s.y + sv.y, dv, b[2 * j + 1]), 0.f);
        ((float2*)&As[w][0])[j] = make_float2(ox, oy);
    }
    __builtin_amdgcn_wave_barrier();

    // attention over layers (wave = node; feature = lane)
    float v[N_LAYER], sc[N_LAYER];
#pragma unroll
    for (int l = 0; l < 3; l++) {
        float val = __half2float(hs16[((size_t)l * N_NODES + n) * 64 + lane]);
        v[l]  = val;
        sc[l] = val * val;
    }
    v[3]  = As[w][lane];
    sc[3] = v[3] * v[3];
#pragma unroll
    for (int off = 32; off > 0; off >>= 1) {
#pragma unroll
        for (int l = 0; l < N_LAYER; l++) sc[l] += __shfl_xor(sc[l], off, 64);
    }
    float m = fmaxf(fmaxf(sc[0], sc[1]), fmaxf(sc[2], sc[3]));
    float e[N_LAYER];
    float sum = 0.f;
#pragma unroll
    for (int l = 0; l < N_LAYER; l++) { e[l] = __expf(sc[l] - m); sum += e[l]; }
    float inv = 1.f / sum;
    float bl = 0.f;
#pragma unroll
    for (int l = 0; l < N_LAYER; l++) bl = fmaf(e[l] * inv, v[l], bl);
    As[w][lane] = bl;                     // own-thread address: ordered after read
    __builtin_amdgcn_wave_barrier();

    if (lane < N_CLASS) {
        float o = bout[lane];
#pragma unroll
        for (int k = 0; k < 64; k++)
            o = fmaf(As[w][k], Wout[k * N_CLASS + lane], o);
        out[(size_t)n * N_CLASS + lane] = o;
    }
}

// ---------------- launch ----------------

extern "C" void kernel_launch(void* const* d_in, const int* in_sizes, int n_in,
                              void* d_out, int out_size, void* d_ws, size_t ws_size,
                              hipStream_t stream) {
    const float* x    = (const float*)d_in[0];
    const float* W0   = (const float*)d_in[1];
    const float* b0   = (const float*)d_in[2];
    const float* Ws   = (const float*)d_in[3];
    const float* bs   = (const float*)d_in[4];
    const float* Wout = (const float*)d_in[5];
    const float* bout = (const float*)d_in[6];
    const int*   ei   = (const int*)d_in[7];
    const int* src = ei;
    const int* dst = ei + N_EDGES;
    float* out = (float*)d_out;

    int*            cnt    = (int*)d_ws;                            // N
    int*            cursor = cnt + N_NODES;                         // N
    unsigned short* csr16  = (unsigned short*)(cursor + N_NODES);   // E ushort
    int*            bktot  = (int*)(csr16 + N_EDGES);               // NBUCK
    int*            bbase  = bktot + NBUCK;                         // NBUCK+1
    int*            bcur   = bbase + NBUCK + 1;                     // NBUCK*BPAD
    float*          dinv   = (float*)(bcur + NBUCK * BPAD);         // N
    __half*         hdA    = (__half*)(dinv + N_NODES);             // N*64
    __half*         hdB    = hdA + (size_t)N_NODES * 64;            // N*64
    __half*         hs16   = hdB + (size_t)N_NODES * 64;            // 3*N*64
    unsigned int*   stag   = (unsigned int*)hs16;                   // E, aliased (build only)

    hipMemsetAsync(bktot, 0, NBUCK * sizeof(int), stream);
    k_hist  <<<NBBLK, 256, 0, stream>>>(dst, bktot);
    k_scanb <<<1, 256, 0, stream>>>(bktot, bbase, bcur);
    k_bucket<<<NBBLK, 256, 0, stream>>>(src, dst, bcur, stag);
    k_csr2  <<<NBUCK, 256, 0, stream>>>(stag, bbase, cnt, cursor, dinv, csr16);

    const int NT = N_NODES / 16;   // 3125 blocks x 1024 threads

    k_gemm0<<<NT, 1024, 0, stream>>>(x, W0, dinv, hdA);

    k_fused<<<NT, 1024, 0, stream>>>((const __half2*)hdA, b0, dinv, cnt, cursor, csr16,
                                     Ws + 0 * 64 * 64, hs16 + (size_t)0 * N_NODES * 64, hdB);
    k_fused<<<NT, 1024, 0, stream>>>((const __half2*)hdB, bs + 0 * 64, dinv, cnt, cursor, csr16,
                                     Ws + 1 * 64 * 64, hs16 + (size_t)1 * N_NODES * 64, hdA);
    k_fused<<<NT, 1024, 0, stream>>>((const __half2*)hdA, bs + 1 * 64, dinv, cnt, cursor, csr16,
                                     Ws + 2 * 64 * 64, hs16 + (size_t)2 * N_NODES * 64, hdB);
    k_last <<<NT, 1024, 0, stream>>>((const __half2*)hdB, bs + 2 * 64, dinv, cnt, cursor, csr16,
                                     hs16, Wout, bout, out);
}

// Round 9
// 269.944 us; speedup vs baseline: 1.1882x; 1.1882x over previous
//
#include <hip/hip_runtime.h>
#include <hip/hip_fp16.h>

#define N_NODES 50000
#define N_HID   64
#define N_LAYER 4
#define N_CLASS 40
#define N_EDGES 800000

#define BSHIFT 8
#define BSIZE  256                                      // nodes per bucket
#define NBUCK  ((N_NODES + BSIZE - 1) / BSIZE)          // 196
#define BPAD   16                                       // bucket-cursor stride (64B)
#define EPT    16                                       // edges per thread (hist/bucket)
#define BKCHUNK (256 * EPT)                             // 4096 edges per block
#define NBBLK  ((N_EDGES + BKCHUNK - 1) / BKCHUNK)      // 196

// ---------------- build: bucket histogram (LDS-aggregated) ----------------

__global__ void k_hist(const int* __restrict__ dst, int* __restrict__ bktot) {
    __shared__ int lh[NBUCK];
    int t = threadIdx.x;
    for (int i = t; i < NBUCK; i += 256) lh[i] = 0;
    __syncthreads();
    int base = blockIdx.x * BKCHUNK;
#pragma unroll
    for (int i = 0; i < EPT; i++) {
        int e = base + i * 256 + t;
        if (e < N_EDGES) atomicAdd(&lh[dst[e] >> BSHIFT], 1);
    }
    __syncthreads();
    for (int i = t; i < NBUCK; i += 256) {
        int v = lh[i];
        if (v) atomicAdd(&bktot[i], v);
    }
}

// single block: exclusive scan of 196 bucket totals -> bbase; init bcur
__global__ void k_scanb(const int* __restrict__ bktot, int* __restrict__ bbase,
                        int* __restrict__ bcur) {
    __shared__ int tmp[256];
    int t = threadIdx.x;
    int v = (t < NBUCK) ? bktot[t] : 0;
    tmp[t] = v;
    __syncthreads();
    for (int off = 1; off < 256; off <<= 1) {
        int u = (t >= off) ? tmp[t - off] : 0;
        __syncthreads();
        tmp[t] += u;
        __syncthreads();
    }
    int excl = tmp[t] - v;
    if (t < NBUCK) { bbase[t] = excl; bcur[t * BPAD] = excl; }
    if (t == NBUCK - 1) bbase[NBUCK] = excl + v;   // = N_EDGES
}

// block-binned append of packed (dst<<16)|src into dst-bucket windows
__global__ void k_bucket(const int* __restrict__ src, const int* __restrict__ dst,
                         int* __restrict__ bcur, unsigned int* __restrict__ stag) {
    __shared__ int lhist[NBUCK];
    __shared__ int gbase[NBUCK];
    int t = threadIdx.x;
    for (int i = t; i < NBUCK; i += 256) lhist[i] = 0;
    __syncthreads();

    int base = blockIdx.x * BKCHUNK;
    unsigned int rec[EPT];
    int br[EPT];
#pragma unroll
    for (int i = 0; i < EPT; i++) {
        int e = base + i * 256 + t;      // coalesced
        if (e < N_EDGES) {
            int d = dst[e], s = src[e];
            int b = d >> BSHIFT;
            int r = atomicAdd(&lhist[b], 1);   // in-block rank within bucket
            rec[i] = ((unsigned int)d << 16) | (unsigned int)s;
            br[i]  = (b << 16) | r;            // r < 4096
        } else {
            br[i] = -1;
        }
    }
    __syncthreads();
    for (int i = t; i < NBUCK; i += 256) {
        int c = lhist[i];
        gbase[i] = c ? atomicAdd(&bcur[i * BPAD], c) : 0;
    }
    __syncthreads();
#pragma unroll
    for (int i = 0; i < EPT; i++) {
        if (br[i] >= 0) {
            int b = br[i] >> 16, r = br[i] & 0xffff;
            stag[gbase[b] + r] = rec[i];
        }
    }
}

// per-bucket: LDS count + scan over the bucket's staging window ->
// cnt / cursor / dinv per node, then scatter src into exact CSR slots.
__global__ void k_csr2(const unsigned int* __restrict__ stag, const int* __restrict__ bbase,
                       int* __restrict__ cnt, int* __restrict__ cursor,
                       float* __restrict__ dinv, unsigned short* __restrict__ csr16) {
    __shared__ int lcnt[BSIZE], ltmp[BSIZE], lcur[BSIZE];
    int b = blockIdx.x, t = threadIdx.x;
    int bstart = bbase[b], bend = bbase[b + 1];
    lcnt[t] = 0;
    __syncthreads();
    for (int i = bstart + t; i < bend; i += 256)
        atomicAdd(&lcnt[(stag[i] >> 16) & (BSIZE - 1)], 1);
    __syncthreads();
    int v = lcnt[t];
    ltmp[t] = v;
    __syncthreads();
    for (int off = 1; off < 256; off <<= 1) {
        int u = (t >= off) ? ltmp[t - off] : 0;
        __syncthreads();
        ltmp[t] += u;
        __syncthreads();
    }
    int cur = bstart + ltmp[t] - v;      // node's CSR row start
    lcur[t] = cur;
    int node = (b << BSHIFT) + t;
    if (node < N_NODES) {
        cnt[node]    = v;
        cursor[node] = cur;
        dinv[node]   = rsqrtf((float)(v + 1));
    }
    __syncthreads();
    for (int i = bstart + t; i < bend; i += 256) {
        unsigned int rec = stag[i];
        int p = atomicAdd(&lcur[(rec >> 16) & (BSIZE - 1)], 1);
        csr16[p] = (unsigned short)rec;
    }
}

// ---------------- layer-0 GEMM: hd = half((x @ W0) * dinv) ----------------
// 256 threads = 4 waves; wave w owns node w. No cross-wave LDS sharing.

__global__ __launch_bounds__(256) void k_gemm0(const float* __restrict__ A,
                                               const float* __restrict__ W,
                                               const float* __restrict__ dinv,
                                               __half* __restrict__ hd) {
    __shared__ float As[4][128];
    int tid = threadIdx.x;
    int w = tid >> 6, j = tid & 63;
    int n = blockIdx.x * 4 + w;

    ((float2*)&As[w][0])[j] = ((const float2*)(A + (size_t)n * 128))[j];  // own-wave stage
    __builtin_amdgcn_wave_barrier();      // same-wave DS ops execute in order

    float acc = 0.f;
#pragma unroll
    for (int k = 0; k < 128; k += 4) {
        float4 a = *(const float4*)&As[w][k];       // wave-uniform broadcast
        acc = fmaf(a.x, W[(k + 0) * 64 + j], acc);
        acc = fmaf(a.y, W[(k + 1) * 64 + j], acc);
        acc = fmaf(a.z, W[(k + 2) * 64 + j], acc);
        acc = fmaf(a.w, W[(k + 3) * 64 + j], acc);
    }
    hd[(size_t)n * 64 + j] = __float2half(acc * dinv[n]);
}

// ---------------- agg for one node by one wave ----------------
// returns (hw-combined) neighbor sum for feature pair j

__device__ __forceinline__ float2 agg_node(const __half2* __restrict__ hd,
                                           const int* __restrict__ cnt,
                                           const int* __restrict__ cursor,
                                           const unsigned short* __restrict__ csr16,
                                           int n, int j, int hw) {
    int k   = cursor[n];
    int end = k + cnt[n];
    float sx = 0.f, sy = 0.f;
    for (; k + 8 <= end; k += 8) {       // 4 gathers in flight per lane-half
        int s0 = csr16[k + hw],     s1 = csr16[k + 2 + hw];
        int s2 = csr16[k + 4 + hw], s3 = csr16[k + 6 + hw];
        float2 v0 = __half22float2(hd[(size_t)s0 * 32 + j]);
        float2 v1 = __half22float2(hd[(size_t)s1 * 32 + j]);
        float2 v2 = __half22float2(hd[(size_t)s2 * 32 + j]);
        float2 v3 = __half22float2(hd[(size_t)s3 * 32 + j]);
        sx += (v0.x + v1.x) + (v2.x + v3.x);
        sy += (v0.y + v1.y) + (v2.y + v3.y);
    }
    if (k + 4 <= end) {
        int s0 = csr16[k + hw], s1 = csr16[k + 2 + hw];
        float2 v0 = __half22float2(hd[(size_t)s0 * 32 + j]);
        float2 v1 = __half22float2(hd[(size_t)s1 * 32 + j]);
        sx += v0.x + v1.x;
        sy += v0.y + v1.y;
        k += 4;
    }
    if (k + 2 <= end) {
        int s0 = csr16[k + hw];
        float2 v0 = __half22float2(hd[(size_t)s0 * 32 + j]);
        sx += v0.x; sy += v0.y;
        k += 2;
    }
    if (hw == 0 && k < end) {
        int s0 = csr16[k];
        float2 v0 = __half22float2(hd[(size_t)s0 * 32 + j]);
        sx += v0.x; sy += v0.y;
    }
    sx += __shfl_xor(sx, 32);
    sy += __shfl_xor(sy, 32);
    return make_float2(sx, sy);
}

// ---------------- fused: agg(layer l) + gemm(layer l+1) ----------------

__global__ __launch_bounds__(256) void k_fused(const __half2* __restrict__ hd_in,
                                               const float* __restrict__ b,
                                               const float* __restrict__ dinv,
                                               const int* __restrict__ cnt,
                                               const int* __restrict__ cursor,
                                               const unsigned short* __restrict__ csr16,
                                               const float* __restrict__ W,
                                               __half* __restrict__ hs_out,
                                               __half* __restrict__ hd_out) {
    __shared__ float As[4][64];
    int tid = threadIdx.x;
    int w = tid >> 6, lane = tid & 63;
    int j = lane & 31, hw = lane >> 5;
    int n = blockIdx.x * 4 + w;

    float2 s = agg_node(hd_in, cnt, cursor, csr16, n, j, hw);
    if (hw == 0) {
        float dv = dinv[n];
        float2 sv = __half22float2(hd_in[(size_t)n * 32 + j]);   // self row
        float ox = fmaxf(fmaf(s.x + sv.x, dv, b[2 * j]), 0.f);
        float oy = fmaxf(fmaf(s.y + sv.y, dv, b[2 * j + 1]), 0.f);
        ((float2*)&As[w][0])[j] = make_float2(ox, oy);
        ((__half2*)hs_out)[(size_t)n * 32 + j] =
            __halves2half2(__float2half(ox), __float2half(oy));
    }
    __builtin_amdgcn_wave_barrier();      // own-wave LDS handoff (in-order DS)

    float acc = 0.f;
#pragma unroll
    for (int k = 0; k < 64; k += 4) {
        float4 a = *(const float4*)&As[w][k];
        acc = fmaf(a.x, W[(k + 0) * 64 + lane], acc);
        acc = fmaf(a.y, W[(k + 1) * 64 + lane], acc);
        acc = fmaf(a.z, W[(k + 2) * 64 + lane], acc);
        acc = fmaf(a.w, W[(k + 3) * 64 + lane], acc);
    }
    hd_out[(size_t)n * 64 + lane] = __float2half(acc * dinv[n]);
}

// ---------------- last: agg(l3) + layer-attention + projection ----------------

__global__ __launch_bounds__(256) void k_last(const __half2* __restrict__ hd_in,
                                              const float* __restrict__ b,
                                              const float* __restrict__ dinv,
                                              const int* __restrict__ cnt,
                                              const int* __restrict__ cursor,
                                              const unsigned short* __restrict__ csr16,
                                              const __half* __restrict__ hs16,
                                              const float* __restrict__ Wout,
                                              const float* __restrict__ bout,
                                              float* __restrict__ out) {
    __shared__ float As[4][64];
    int tid = threadIdx.x;
    int w = tid >> 6, lane = tid & 63;
    int j = lane & 31, hw = lane >> 5;
    int n = blockIdx.x * 4 + w;

    float2 s = agg_node(hd_in, cnt, cursor, csr16, n, j, hw);
    if (hw == 0) {
        float dv = dinv[n];
        float2 sv = __half22float2(hd_in[(size_t)n * 32 + j]);
        float ox = fmaxf(fmaf(s.x + sv.x, dv, b[2 * j]), 0.f);
        float oy = fmaxf(fmaf(s.y + sv.y, dv, b[2 * j + 1]), 0.f);
        ((float2*)&As[w][0])[j] = make_float2(ox, oy);
    }
    __builtin_amdgcn_wave_barrier();

    // attention over layers (wave = node; feature = lane)
    float v[N_LAYER], sc[N_LAYER];
#pragma unroll
    for (int l = 0; l < 3; l++) {
        float val = __half2float(hs16[((size_t)l * N_NODES + n) * 64 + lane]);
        v[l]  = val;
        sc[l] = val * val;
    }
    v[3]  = As[w][lane];
    sc[3] = v[3] * v[3];
#pragma unroll
    for (int off = 32; off > 0; off >>= 1) {
#pragma unroll
        for (int l = 0; l < N_LAYER; l++) sc[l] += __shfl_xor(sc[l], off, 64);
    }
    float m = fmaxf(fmaxf(sc[0], sc[1]), fmaxf(sc[2], sc[3]));
    float e[N_LAYER];
    float sum = 0.f;
#pragma unroll
    for (int l = 0; l < N_LAYER; l++) { e[l] = __expf(sc[l] - m); sum += e[l]; }
    float inv = 1.f / sum;
    float bl = 0.f;
#pragma unroll
    for (int l = 0; l < N_LAYER; l++) bl = fmaf(e[l] * inv, v[l], bl);
    As[w][lane] = bl;                     // own-thread address: ordered after read
    __builtin_amdgcn_wave_barrier();

    if (lane < N_CLASS) {
        float o = bout[lane];
#pragma unroll
        for (int k = 0; k < 64; k++)
            o = fmaf(As[w][k], Wout[k * N_CLASS + lane], o);
        out[(size_t)n * N_CLASS + lane] = o;
    }
}

// ---------------- launch ----------------

extern "C" void kernel_launch(void* const* d_in, const int* in_sizes, int n_in,
                              void* d_out, int out_size, void* d_ws, size_t ws_size,
                              hipStream_t stream) {
    const float* x    = (const float*)d_in[0];
    const float* W0   = (const float*)d_in[1];
    const float* b0   = (const float*)d_in[2];
    const float* Ws   = (const float*)d_in[3];
    const float* bs   = (const float*)d_in[4];
    const float* Wout = (const float*)d_in[5];
    const float* bout = (const float*)d_in[6];
    const int*   ei   = (const int*)d_in[7];
    const int* src = ei;
    const int* dst = ei + N_EDGES;
    float* out = (float*)d_out;

    int*            cnt    = (int*)d_ws;                            // N
    int*            cursor = cnt + N_NODES;                         // N
    unsigned short* csr16  = (unsigned short*)(cursor + N_NODES);   // E ushort
    int*            bktot  = (int*)(csr16 + N_EDGES);               // NBUCK
    int*            bbase  = bktot + NBUCK;                         // NBUCK+1
    int*            bcur   = bbase + NBUCK + 1;                     // NBUCK*BPAD
    float*          dinv   = (float*)(bcur + NBUCK * BPAD);         // N
    __half*         hdA    = (__half*)(dinv + N_NODES);             // N*64
    __half*         hdB    = hdA + (size_t)N_NODES * 64;            // N*64
    __half*         hs16   = hdB + (size_t)N_NODES * 64;            // 3*N*64
    unsigned int*   stag   = (unsigned int*)hs16;                   // E, aliased (build only)

    hipMemsetAsync(bktot, 0, NBUCK * sizeof(int), stream);
    k_hist  <<<NBBLK, 256, 0, stream>>>(dst, bktot);
    k_scanb <<<1, 256, 0, stream>>>(bktot, bbase, bcur);
    k_bucket<<<NBBLK, 256, 0, stream>>>(src, dst, bcur, stag);
    k_csr2  <<<NBUCK, 256, 0, stream>>>(stag, bbase, cnt, cursor, dinv, csr16);

    const int NB = N_NODES / 4;   // 12500 blocks x 256 threads, wave = node

    k_gemm0<<<NB, 256, 0, stream>>>(x, W0, dinv, hdA);

    k_fused<<<NB, 256, 0, stream>>>((const __half2*)hdA, b0, dinv, cnt, cursor, csr16,
                                    Ws + 0 * 64 * 64, hs16 + (size_t)0 * N_NODES * 64, hdB);
    k_fused<<<NB, 256, 0, stream>>>((const __half2*)hdB, bs + 0 * 64, dinv, cnt, cursor, csr16,
                                    Ws + 1 * 64 * 64, hs16 + (size_t)1 * N_NODES * 64, hdA);
    k_fused<<<NB, 256, 0, stream>>>((const __half2*)hdA, bs + 1 * 64, dinv, cnt, cursor, csr16,
                                    Ws + 2 * 64 * 64, hs16 + (size_t)2 * N_NODES * 64, hdB);
    k_last <<<NB, 256, 0, stream>>>((const __half2*)hdB, bs + 2 * 64, dinv, cnt, cursor, csr16,
                                    hs16, Wout, bout, out);
}

// Round 10
// 210.555 us; speedup vs baseline: 1.5234x; 1.2821x over previous
//
#include <hip/hip_runtime.h>
#include <hip/hip_fp16.h>

#define N_NODES 50000
#define N_HID   64
#define N_LAYER 4
#define N_CLASS 40
#define N_EDGES 800000

#define BSHIFT 8
#define BSIZE  256                                      // nodes per bucket
#define NBUCK  ((N_NODES + BSIZE - 1) / BSIZE)          // 196
#define BPAD   16                                      // bucket-cursor stride (64B)
#define EPT    16                                      // edges per thread (hist/bucket)
#define BKCHUNK (256 * EPT)                             // 4096 edges per block
#define NBBLK  ((N_EDGES + BKCHUNK - 1) / BKCHUNK)      // 196

// ---------------- build: bucket histogram (LDS-aggregated) ----------------

__global__ void k_hist(const int* __restrict__ dst, int* __restrict__ bktot) {
    __shared__ int lh[NBUCK];
    int t = threadIdx.x;
    for (int i = t; i < NBUCK; i += 256) lh[i] = 0;
    __syncthreads();
    int base = blockIdx.x * BKCHUNK;
#pragma unroll
    for (int i = 0; i < EPT; i++) {
        int e = base + i * 256 + t;
        if (e < N_EDGES) atomicAdd(&lh[dst[e] >> BSHIFT], 1);
    }
    __syncthreads();
    for (int i = t; i < NBUCK; i += 256) {
        int v = lh[i];
        if (v) atomicAdd(&bktot[i], v);
    }
}

// single block: exclusive scan of 196 bucket totals -> bbase; init bcur
__global__ void k_scanb(const int* __restrict__ bktot, int* __restrict__ bbase,
                        int* __restrict__ bcur) {
    __shared__ int tmp[256];
    int t = threadIdx.x;
    int v = (t < NBUCK) ? bktot[t] : 0;
    tmp[t] = v;
    __syncthreads();
    for (int off = 1; off < 256; off <<= 1) {
        int u = (t >= off) ? tmp[t - off] : 0;
        __syncthreads();
        tmp[t] += u;
        __syncthreads();
    }
    int excl = tmp[t] - v;
    if (t < NBUCK) { bbase[t] = excl; bcur[t * BPAD] = excl; }
    if (t == NBUCK - 1) bbase[NBUCK] = excl + v;   // = N_EDGES
}

// block-binned append of packed (dst<<16)|src into dst-bucket windows
__global__ void k_bucket(const int* __restrict__ src, const int* __restrict__ dst,
                         int* __restrict__ bcur, unsigned int* __restrict__ stag) {
    __shared__ int lhist[NBUCK];
    __shared__ int gbase[NBUCK];
    int t = threadIdx.x;
    for (int i = t; i < NBUCK; i += 256) lhist[i] = 0;
    __syncthreads();

    int base = blockIdx.x * BKCHUNK;
    unsigned int rec[EPT];
    int br[EPT];
#pragma unroll
    for (int i = 0; i < EPT; i++) {
        int e = base + i * 256 + t;      // coalesced
        if (e < N_EDGES) {
            int d = dst[e], s = src[e];
            int b = d >> BSHIFT;
            int r = atomicAdd(&lhist[b], 1);   // in-block rank within bucket
            rec[i] = ((unsigned int)d << 16) | (unsigned int)s;
            br[i]  = (b << 16) | r;            // r < 4096
        } else {
            br[i] = -1;
        }
    }
    __syncthreads();
    for (int i = t; i < NBUCK; i += 256) {
        int c = lhist[i];
        gbase[i] = c ? atomicAdd(&bcur[i * BPAD], c) : 0;
    }
    __syncthreads();
#pragma unroll
    for (int i = 0; i < EPT; i++) {
        if (br[i] >= 0) {
            int b = br[i] >> 16, r = br[i] & 0xffff;
            stag[gbase[b] + r] = rec[i];
        }
    }
}

// per-bucket: LDS count + scan over the bucket's staging window ->
// cnt / cursor / dinv per node, then scatter src into exact CSR slots.
__global__ void k_csr2(const unsigned int* __restrict__ stag, const int* __restrict__ bbase,
                       int* __restrict__ cnt, int* __restrict__ cursor,
                       float* __restrict__ dinv, unsigned short* __restrict__ csr16) {
    __shared__ int lcnt[BSIZE], ltmp[BSIZE], lcur[BSIZE];
    int b = blockIdx.x, t = threadIdx.x;
    int bstart = bbase[b], bend = bbase[b + 1];
    lcnt[t] = 0;
    __syncthreads();
    for (int i = bstart + t; i < bend; i += 256)
        atomicAdd(&lcnt[(stag[i] >> 16) & (BSIZE - 1)], 1);
    __syncthreads();
    int v = lcnt[t];
    ltmp[t] = v;
    __syncthreads();
    for (int off = 1; off < 256; off <<= 1) {
        int u = (t >= off) ? ltmp[t - off] : 0;
        __syncthreads();
        ltmp[t] += u;
        __syncthreads();
    }
    int cur = bstart + ltmp[t] - v;      // node's CSR row start
    lcur[t] = cur;
    int node = (b << BSHIFT) + t;
    if (node < N_NODES) {
        cnt[node]    = v;
        cursor[node] = cur;
        dinv[node]   = rsqrtf((float)(v + 1));
    }
    __syncthreads();
    for (int i = bstart + t; i < bend; i += 256) {
        unsigned int rec = stag[i];
        int p = atomicAdd(&lcur[(rec >> 16) & (BSIZE - 1)], 1);
        csr16[p] = (unsigned short)rec;
    }
}

// ---------------- layer-0 GEMM (tiled, 4 acc/thread): hd = half((x@W0)*dinv) ----------------
// 256 threads = 16 nodes x 64 cols, 4 nodes per thread -> 4x W reuse.

__global__ __launch_bounds__(256) void k_gemm0(const float* __restrict__ A,
                                               const float* __restrict__ W,
                                               const float* __restrict__ dinv,
                                               __half* __restrict__ hd) {
    __shared__ float As[16][128];
    int tid = threadIdx.x;
    int j  = tid & 63;
    int nl = tid >> 6;              // 0..3
    int node0 = blockIdx.x * 16;

    const float4* srcp = (const float4*)(A + (size_t)node0 * 128);
    float4* dstp = (float4*)&As[0][0];
    for (int idx = tid; idx < 16 * 128 / 4; idx += 256) dstp[idx] = srcp[idx];
    __syncthreads();

    float acc[4] = {0.f, 0.f, 0.f, 0.f};
#pragma unroll
    for (int k = 0; k < 128; k += 4) {
        float4 a0 = *(const float4*)&As[nl * 4 + 0][k];   // wave-uniform broadcast
        float4 a1 = *(const float4*)&As[nl * 4 + 1][k];
        float4 a2 = *(const float4*)&As[nl * 4 + 2][k];
        float4 a3 = *(const float4*)&As[nl * 4 + 3][k];
        float w0 = W[(k + 0) * 64 + j];
        float w1 = W[(k + 1) * 64 + j];
        float w2 = W[(k + 2) * 64 + j];
        float w3 = W[(k + 3) * 64 + j];
        acc[0] = fmaf(a0.w, w3, fmaf(a0.z, w2, fmaf(a0.y, w1, fmaf(a0.x, w0, acc[0]))));
        acc[1] = fmaf(a1.w, w3, fmaf(a1.z, w2, fmaf(a1.y, w1, fmaf(a1.x, w0, acc[1]))));
        acc[2] = fmaf(a2.w, w3, fmaf(a2.z, w2, fmaf(a2.y, w1, fmaf(a2.x, w0, acc[2]))));
        acc[3] = fmaf(a3.w, w3, fmaf(a3.z, w2, fmaf(a3.y, w1, fmaf(a3.x, w0, acc[3]))));
    }
#pragma unroll
    for (int i = 0; i < 4; i++) {
        int n = node0 + nl * 4 + i;
        hd[(size_t)n * 64 + j] = __float2half(acc[i] * dinv[n]);
    }
}

// ---------------- agg for one node by one wave ----------------

__device__ __forceinline__ float2 agg_node(const __half2* __restrict__ hd,
                                           const int* __restrict__ cnt,
                                           const int* __restrict__ cursor,
                                           const unsigned short* __restrict__ csr16,
                                           int n, int j, int hw) {
    int k   = cursor[n];
    int end = k + cnt[n];
    float sx = 0.f, sy = 0.f;
    for (; k + 8 <= end; k += 8) {       // 4 gathers in flight per lane-half
        int s0 = csr16[k + hw],     s1 = csr16[k + 2 + hw];
        int s2 = csr16[k + 4 + hw], s3 = csr16[k + 6 + hw];
        float2 v0 = __half22float2(hd[(size_t)s0 * 32 + j]);
        float2 v1 = __half22float2(hd[(size_t)s1 * 32 + j]);
        float2 v2 = __half22float2(hd[(size_t)s2 * 32 + j]);
        float2 v3 = __half22float2(hd[(size_t)s3 * 32 + j]);
        sx += (v0.x + v1.x) + (v2.x + v3.x);
        sy += (v0.y + v1.y) + (v2.y + v3.y);
    }
    if (k + 4 <= end) {
        int s0 = csr16[k + hw], s1 = csr16[k + 2 + hw];
        float2 v0 = __half22float2(hd[(size_t)s0 * 32 + j]);
        float2 v1 = __half22float2(hd[(size_t)s1 * 32 + j]);
        sx += v0.x + v1.x;
        sy += v0.y + v1.y;
        k += 4;
    }
    if (k + 2 <= end) {
        int s0 = csr16[k + hw];
        float2 v0 = __half22float2(hd[(size_t)s0 * 32 + j]);
        sx += v0.x; sy += v0.y;
        k += 2;
    }
    if (hw == 0 && k < end) {
        int s0 = csr16[k];
        float2 v0 = __half22float2(hd[(size_t)s0 * 32 + j]);
        sx += v0.x; sy += v0.y;
    }
    sx += __shfl_xor(sx, 32);
    sy += __shfl_xor(sy, 32);
    return make_float2(sx, sy);
}

// ---------------- fused: agg(layer l, wave=node) + gemm(layer l+1, wave0 4-acc) ----------------

__global__ __launch_bounds__(256) void k_fused(const __half2* __restrict__ hd_in,
                                               const float* __restrict__ b,
                                               const float* __restrict__ dinv,
                                               const int* __restrict__ cnt,
                                               const int* __restrict__ cursor,
                                               const unsigned short* __restrict__ csr16,
                                               const float* __restrict__ W,
                                               __half* __restrict__ hs_out,
                                               __half* __restrict__ hd_out) {
    __shared__ float As[4][64];
    int tid = threadIdx.x;
    int w = tid >> 6, lane = tid & 63;
    int j = lane & 31, hw = lane >> 5;
    int node0 = blockIdx.x * 4;
    int n = node0 + w;

    float2 s = agg_node(hd_in, cnt, cursor, csr16, n, j, hw);
    if (hw == 0) {
        float dv = dinv[n];
        float2 sv = __half22float2(hd_in[(size_t)n * 32 + j]);   // self row
        float ox = fmaxf(fmaf(s.x + sv.x, dv, b[2 * j]), 0.f);
        float oy = fmaxf(fmaf(s.y + sv.y, dv, b[2 * j + 1]), 0.f);
        ((float2*)&As[w][0])[j] = make_float2(ox, oy);
        ((__half2*)hs_out)[(size_t)n * 32 + j] =
            __halves2half2(__float2half(ox), __float2half(oy));
    }
    __syncthreads();

    // wave 0: gemm for the block's 4 nodes, 4 acc/thread (4x W reuse, ILP 4)
    if (tid < 64) {
        float acc[4] = {0.f, 0.f, 0.f, 0.f};
#pragma unroll
        for (int k = 0; k < 64; k += 4) {
            float4 a0 = *(const float4*)&As[0][k];   // wave-uniform broadcasts
            float4 a1 = *(const float4*)&As[1][k];
            float4 a2 = *(const float4*)&As[2][k];
            float4 a3 = *(const float4*)&As[3][k];
            float w0 = W[(k + 0) * 64 + tid];
            float w1 = W[(k + 1) * 64 + tid];
            float w2 = W[(k + 2) * 64 + tid];
            float w3 = W[(k + 3) * 64 + tid];
            acc[0] = fmaf(a0.w, w3, fmaf(a0.z, w2, fmaf(a0.y, w1, fmaf(a0.x, w0, acc[0]))));
            acc[1] = fmaf(a1.w, w3, fmaf(a1.z, w2, fmaf(a1.y, w1, fmaf(a1.x, w0, acc[1]))));
            acc[2] = fmaf(a2.w, w3, fmaf(a2.z, w2, fmaf(a2.y, w1, fmaf(a2.x, w0, acc[2]))));
            acc[3] = fmaf(a3.w, w3, fmaf(a3.z, w2, fmaf(a3.y, w1, fmaf(a3.x, w0, acc[3]))));
        }
#pragma unroll
        for (int i = 0; i < 4; i++) {
            int nn = node0 + i;
            hd_out[(size_t)nn * 64 + tid] = __float2half(acc[i] * dinv[nn]);
        }
    }
}

// ---------------- last: agg(l3) + attention + projection(wave0 4-acc) ----------------

__global__ __launch_bounds__(256) void k_last(const __half2* __restrict__ hd_in,
                                              const float* __restrict__ b,
                                              const float* __restrict__ dinv,
                                              const int* __restrict__ cnt,
                                              const int* __restrict__ cursor,
                                              const unsigned short* __restrict__ csr16,
                                              const __half* __restrict__ hs16,
                                              const float* __restrict__ Wout,
                                              const float* __restrict__ bout,
                                              float* __restrict__ out) {
    __shared__ float As[4][64];
    int tid = threadIdx.x;
    int w = tid >> 6, lane = tid & 63;
    int j = lane & 31, hw = lane >> 5;
    int node0 = blockIdx.x * 4;
    int n = node0 + w;

    float2 s = agg_node(hd_in, cnt, cursor, csr16, n, j, hw);
    if (hw == 0) {
        float dv = dinv[n];
        float2 sv = __half22float2(hd_in[(size_t)n * 32 + j]);
        float ox = fmaxf(fmaf(s.x + sv.x, dv, b[2 * j]), 0.f);
        float oy = fmaxf(fmaf(s.y + sv.y, dv, b[2 * j + 1]), 0.f);
        ((float2*)&As[w][0])[j] = make_float2(ox, oy);
    }
    __builtin_amdgcn_wave_barrier();

    // attention over layers (wave = node; feature = lane)
    float v[N_LAYER], sc[N_LAYER];
#pragma unroll
    for (int l = 0; l < 3; l++) {
        float val = __half2float(hs16[((size_t)l * N_NODES + n) * 64 + lane]);
        v[l]  = val;
        sc[l] = val * val;
    }
    v[3]  = As[w][lane];
    sc[3] = v[3] * v[3];
#pragma unroll
    for (int off = 32; off > 0; off >>= 1) {
#pragma unroll
        for (int l = 0; l < N_LAYER; l++) sc[l] += __shfl_xor(sc[l], off, 64);
    }
    float m = fmaxf(fmaxf(sc[0], sc[1]), fmaxf(sc[2], sc[3]));
    float e[N_LAYER];
    float sum = 0.f;
#pragma unroll
    for (int l = 0; l < N_LAYER; l++) { e[l] = __expf(sc[l] - m); sum += e[l]; }
    float inv = 1.f / sum;
    float bl = 0.f;
#pragma unroll
    for (int l = 0; l < N_LAYER; l++) bl = fmaf(e[l] * inv, v[l], bl);
    As[w][lane] = bl;                     // own-thread address: ordered after read
    __syncthreads();

    // wave 0: projection for the block's 4 nodes, 4 acc/thread
    if (tid < 64 && tid < N_CLASS) {
        float acc[4] = {bout[tid], bout[tid], bout[tid], bout[tid]};
#pragma unroll
        for (int k = 0; k < 64; k += 4) {
            float4 a0 = *(const float4*)&As[0][k];
            float4 a1 = *(const float4*)&As[1][k];
            float4 a2 = *(const float4*)&As[2][k];
            float4 a3 = *(const float4*)&As[3][k];
            float w0 = Wout[(k + 0) * N_CLASS + tid];
            float w1 = Wout[(k + 1) * N_CLASS + tid];
            float w2 = Wout[(k + 2) * N_CLASS + tid];
            float w3 = Wout[(k + 3) * N_CLASS + tid];
            acc[0] = fmaf(a0.w, w3, fmaf(a0.z, w2, fmaf(a0.y, w1, fmaf(a0.x, w0, acc[0]))));
            acc[1] = fmaf(a1.w, w3, fmaf(a1.z, w2, fmaf(a1.y, w1, fmaf(a1.x, w0, acc[1]))));
            acc[2] = fmaf(a2.w, w3, fmaf(a2.z, w2, fmaf(a2.y, w1, fmaf(a2.x, w0, acc[2]))));
            acc[3] = fmaf(a3.w, w3, fmaf(a3.z, w2, fmaf(a3.y, w1, fmaf(a3.x, w0, acc[3]))));
        }
#pragma unroll
        for (int i = 0; i < 4; i++)
            out[(size_t)(node0 + i) * N_CLASS + tid] = acc[i];
    }
}

// ---------------- launch ----------------

extern "C" void kernel_launch(void* const* d_in, const int* in_sizes, int n_in,
                              void* d_out, int out_size, void* d_ws, size_t ws_size,
                              hipStream_t stream) {
    const float* x    = (const float*)d_in[0];
    const float* W0   = (const float*)d_in[1];
    const float* b0   = (const float*)d_in[2];
    const float* Ws   = (const float*)d_in[3];
    const float* bs   = (const float*)d_in[4];
    const float* Wout = (const float*)d_in[5];
    const float* bout = (const float*)d_in[6];
    const int*   ei   = (const int*)d_in[7];
    const int* src = ei;
    const int* dst = ei + N_EDGES;
    float* out = (float*)d_out;

    int*            cnt    = (int*)d_ws;                            // N
    int*            cursor = cnt + N_NODES;                         // N
    unsigned short* csr16  = (unsigned short*)(cursor + N_NODES);   // E ushort
    int*            bktot  = (int*)(csr16 + N_EDGES);               // NBUCK
    int*            bbase  = bktot + NBUCK;                         // NBUCK+1
    int*            bcur   = bbase + NBUCK + 1;                     // NBUCK*BPAD
    float*          dinv   = (float*)(bcur + NBUCK * BPAD);         // N
    __half*         hdA    = (__half*)(dinv + N_NODES);             // N*64
    __half*         hdB    = hdA + (size_t)N_NODES * 64;            // N*64
    __half*         hs16   = hdB + (size_t)N_NODES * 64;            // 3*N*64
    unsigned int*   stag   = (unsigned int*)hs16;                   // E, aliased (build only)

    hipMemsetAsync(bktot, 0, NBUCK * sizeof(int), stream);
    k_hist  <<<NBBLK, 256, 0, stream>>>(dst, bktot);
    k_scanb <<<1, 256, 0, stream>>>(bktot, bbase, bcur);
    k_bucket<<<NBBLK, 256, 0, stream>>>(src, dst, bcur, stag);
    k_csr2  <<<NBUCK, 256, 0, stream>>>(stag, bbase, cnt, cursor, dinv, csr16);

    k_gemm0<<<N_NODES / 16, 256, 0, stream>>>(x, W0, dinv, hdA);

    const int NB = N_NODES / 4;   // 12500 blocks x 256 threads, wave = node (agg)

    k_fused<<<NB, 256, 0, stream>>>((const __half2*)hdA, b0, dinv, cnt, cursor, csr16,
                                    Ws + 0 * 64 * 64, hs16 + (size_t)0 * N_NODES * 64, hdB);
    k_fused<<<NB, 256, 0, stream>>>((const __half2*)hdB, bs + 0 * 64, dinv, cnt, cursor, csr16,
                                    Ws + 1 * 64 * 64, hs16 + (size_t)1 * N_NODES * 64, hdA);
    k_fused<<<NB, 256, 0, stream>>>((const __half2*)hdA, bs + 1 * 64, dinv, cnt, cursor, csr16,
                                    Ws + 2 * 64 * 64, hs16 + (size_t)2 * N_NODES * 64, hdB);
    k_last <<<NB, 256, 0, stream>>>((const __half2*)hdB, bs + 2 * 64, dinv, cnt, cursor, csr16,
                                    hs16, Wout, bout, out);
}

// Round 11
// 210.396 us; speedup vs baseline: 1.5246x; 1.0008x over previous
//
#include <hip/hip_runtime.h>
#include <hip/hip_fp16.h>

#define N_NODES 50000
#define N_HID   64
#define N_LAYER 4
#define N_CLASS 40
#define N_EDGES 800000

#define BSHIFT 8
#define BSIZE  256                                      // nodes per bucket
#define NBUCK  ((N_NODES + BSIZE - 1) / BSIZE)          // 196
#define BPAD   16                                      // bucket-cursor stride (64B)
#define EPT    16                                      // edges per thread (hist/bucket)
#define BKCHUNK (256 * EPT)                             // 4096 edges per block
#define NBBLK  ((N_EDGES + BKCHUNK - 1) / BKCHUNK)      // 196

// ---------------- build: zero bucket totals (replaces pathological hipMemsetAsync) ----------------

__global__ void k_zerob(int* __restrict__ bktot) {
    int t = threadIdx.x;
    if (t < NBUCK) bktot[t] = 0;
}

// ---------------- build: bucket histogram (LDS-aggregated) ----------------

__global__ void k_hist(const int* __restrict__ dst, int* __restrict__ bktot) {
    __shared__ int lh[NBUCK];
    int t = threadIdx.x;
    for (int i = t; i < NBUCK; i += 256) lh[i] = 0;
    __syncthreads();
    int base = blockIdx.x * BKCHUNK;
#pragma unroll
    for (int i = 0; i < EPT; i++) {
        int e = base + i * 256 + t;
        if (e < N_EDGES) atomicAdd(&lh[dst[e] >> BSHIFT], 1);
    }
    __syncthreads();
    for (int i = t; i < NBUCK; i += 256) {
        int v = lh[i];
        if (v) atomicAdd(&bktot[i], v);
    }
}

// single block: exclusive scan of 196 bucket totals -> bbase; init bcur
__global__ void k_scanb(const int* __restrict__ bktot, int* __restrict__ bbase,
                        int* __restrict__ bcur) {
    __shared__ int tmp[256];
    int t = threadIdx.x;
    int v = (t < NBUCK) ? bktot[t] : 0;
    tmp[t] = v;
    __syncthreads();
    for (int off = 1; off < 256; off <<= 1) {
        int u = (t >= off) ? tmp[t - off] : 0;
        __syncthreads();
        tmp[t] += u;
        __syncthreads();
    }
    int excl = tmp[t] - v;
    if (t < NBUCK) { bbase[t] = excl; bcur[t * BPAD] = excl; }
    if (t == NBUCK - 1) bbase[NBUCK] = excl + v;   // = N_EDGES
}

// block-binned append of packed (dst<<16)|src into dst-bucket windows
__global__ void k_bucket(const int* __restrict__ src, const int* __restrict__ dst,
                         int* __restrict__ bcur, unsigned int* __restrict__ stag) {
    __shared__ int lhist[NBUCK];
    __shared__ int gbase[NBUCK];
    int t = threadIdx.x;
    for (int i = t; i < NBUCK; i += 256) lhist[i] = 0;
    __syncthreads();

    int base = blockIdx.x * BKCHUNK;
    unsigned int rec[EPT];
    int br[EPT];
#pragma unroll
    for (int i = 0; i < EPT; i++) {
        int e = base + i * 256 + t;      // coalesced
        if (e < N_EDGES) {
            int d = dst[e], s = src[e];
            int b = d >> BSHIFT;
            int r = atomicAdd(&lhist[b], 1);   // in-block rank within bucket
            rec[i] = ((unsigned int)d << 16) | (unsigned int)s;
            br[i]  = (b << 16) | r;            // r < 4096
        } else {
            br[i] = -1;
        }
    }
    __syncthreads();
    for (int i = t; i < NBUCK; i += 256) {
        int c = lhist[i];
        gbase[i] = c ? atomicAdd(&bcur[i * BPAD], c) : 0;
    }
    __syncthreads();
#pragma unroll
    for (int i = 0; i < EPT; i++) {
        if (br[i] >= 0) {
            int b = br[i] >> 16, r = br[i] & 0xffff;
            stag[gbase[b] + r] = rec[i];
        }
    }
}

// per-bucket: LDS count + scan over the bucket's staging window ->
// cnt / cursor / dinv per node, then scatter src into exact CSR slots.
__global__ void k_csr2(const unsigned int* __restrict__ stag, const int* __restrict__ bbase,
                       int* __restrict__ cnt, int* __restrict__ cursor,
                       float* __restrict__ dinv, unsigned short* __restrict__ csr16) {
    __shared__ int lcnt[BSIZE], ltmp[BSIZE], lcur[BSIZE];
    int b = blockIdx.x, t = threadIdx.x;
    int bstart = bbase[b], bend = bbase[b + 1];
    lcnt[t] = 0;
    __syncthreads();
    for (int i = bstart + t; i < bend; i += 256)
        atomicAdd(&lcnt[(stag[i] >> 16) & (BSIZE - 1)], 1);
    __syncthreads();
    int v = lcnt[t];
    ltmp[t] = v;
    __syncthreads();
    for (int off = 1; off < 256; off <<= 1) {
        int u = (t >= off) ? ltmp[t - off] : 0;
        __syncthreads();
        ltmp[t] += u;
        __syncthreads();
    }
    int cur = bstart + ltmp[t] - v;      // node's CSR row start
    lcur[t] = cur;
    int node = (b << BSHIFT) + t;
    if (node < N_NODES) {
        cnt[node]    = v;
        cursor[node] = cur;
        dinv[node]   = rsqrtf((float)(v + 1));
    }
    __syncthreads();
    for (int i = bstart + t; i < bend; i += 256) {
        unsigned int rec = stag[i];
        int p = atomicAdd(&lcur[(rec >> 16) & (BSIZE - 1)], 1);
        csr16[p] = (unsigned short)rec;
    }
}

// ---------------- layer-0 GEMM (tiled, 4 acc/thread): hd = half((x@W0)*dinv) ----------------

__global__ __launch_bounds__(256) void k_gemm0(const float* __restrict__ A,
                                               const float* __restrict__ W,
                                               const float* __restrict__ dinv,
                                               __half* __restrict__ hd) {
    __shared__ float As[16][128];
    int tid = threadIdx.x;
    int j  = tid & 63;
    int nl = tid >> 6;              // 0..3
    int node0 = blockIdx.x * 16;

    const float4* srcp = (const float4*)(A + (size_t)node0 * 128);
    float4* dstp = (float4*)&As[0][0];
    for (int idx = tid; idx < 16 * 128 / 4; idx += 256) dstp[idx] = srcp[idx];
    __syncthreads();

    float acc[4] = {0.f, 0.f, 0.f, 0.f};
#pragma unroll
    for (int k = 0; k < 128; k += 4) {
        float4 a0 = *(const float4*)&As[nl * 4 + 0][k];   // wave-uniform broadcast
        float4 a1 = *(const float4*)&As[nl * 4 + 1][k];
        float4 a2 = *(const float4*)&As[nl * 4 + 2][k];
        float4 a3 = *(const float4*)&As[nl * 4 + 3][k];
        float w0 = W[(k + 0) * 64 + j];
        float w1 = W[(k + 1) * 64 + j];
        float w2 = W[(k + 2) * 64 + j];
        float w3 = W[(k + 3) * 64 + j];
        acc[0] = fmaf(a0.w, w3, fmaf(a0.z, w2, fmaf(a0.y, w1, fmaf(a0.x, w0, acc[0]))));
        acc[1] = fmaf(a1.w, w3, fmaf(a1.z, w2, fmaf(a1.y, w1, fmaf(a1.x, w0, acc[1]))));
        acc[2] = fmaf(a2.w, w3, fmaf(a2.z, w2, fmaf(a2.y, w1, fmaf(a2.x, w0, acc[2]))));
        acc[3] = fmaf(a3.w, w3, fmaf(a3.z, w2, fmaf(a3.y, w1, fmaf(a3.x, w0, acc[3]))));
    }
#pragma unroll
    for (int i = 0; i < 4; i++) {
        int n = node0 + nl * 4 + i;
        hd[(size_t)n * 64 + j] = __float2half(acc[i] * dinv[n]);
    }
}

// ---------------- agg for one node by one wave ----------------

__device__ __forceinline__ float2 agg_node(const __half2* __restrict__ hd,
                                           const int* __restrict__ cnt,
                                           const int* __restrict__ cursor,
                                           const unsigned short* __restrict__ csr16,
                                           int n, int j, int hw) {
    int k   = cursor[n];
    int end = k + cnt[n];
    float sx = 0.f, sy = 0.f;
    for (; k + 8 <= end; k += 8) {       // 4 gathers in flight per lane-half
        int s0 = csr16[k + hw],     s1 = csr16[k + 2 + hw];
        int s2 = csr16[k + 4 + hw], s3 = csr16[k + 6 + hw];
        float2 v0 = __half22float2(hd[(size_t)s0 * 32 + j]);
        float2 v1 = __half22float2(hd[(size_t)s1 * 32 + j]);
        float2 v2 = __half22float2(hd[(size_t)s2 * 32 + j]);
        float2 v3 = __half22float2(hd[(size_t)s3 * 32 + j]);
        sx += (v0.x + v1.x) + (v2.x + v3.x);
        sy += (v0.y + v1.y) + (v2.y + v3.y);
    }
    if (k + 4 <= end) {
        int s0 = csr16[k + hw], s1 = csr16[k + 2 + hw];
        float2 v0 = __half22float2(hd[(size_t)s0 * 32 + j]);
        float2 v1 = __half22float2(hd[(size_t)s1 * 32 + j]);
        sx += v0.x + v1.x;
        sy += v0.y + v1.y;
        k += 4;
    }
    if (k + 2 <= end) {
        int s0 = csr16[k + hw];
        float2 v0 = __half22float2(hd[(size_t)s0 * 32 + j]);
        sx += v0.x; sy += v0.y;
        k += 2;
    }
    if (hw == 0 && k < end) {
        int s0 = csr16[k];
        float2 v0 = __half22float2(hd[(size_t)s0 * 32 + j]);
        sx += v0.x; sy += v0.y;
    }
    sx += __shfl_xor(sx, 32);
    sy += __shfl_xor(sy, 32);
    return make_float2(sx, sy);
}

// ---------------- fused: agg(layer l, wave=node) + gemm(layer l+1, wave0 4-acc) ----------------

__global__ __launch_bounds__(256) void k_fused(const __half2* __restrict__ hd_in,
                                               const float* __restrict__ b,
                                               const float* __restrict__ dinv,
                                               const int* __restrict__ cnt,
                                               const int* __restrict__ cursor,
                                               const unsigned short* __restrict__ csr16,
                                               const float* __restrict__ W,
                                               __half* __restrict__ hs_out,
                                               __half* __restrict__ hd_out) {
    __shared__ float As[4][64];
    int tid = threadIdx.x;
    int w = tid >> 6, lane = tid & 63;
    int j = lane & 31, hw = lane >> 5;
    int node0 = blockIdx.x * 4;
    int n = node0 + w;

    float2 s = agg_node(hd_in, cnt, cursor, csr16, n, j, hw);
    if (hw == 0) {
        float dv = dinv[n];
        float2 sv = __half22float2(hd_in[(size_t)n * 32 + j]);   // self row
        float ox = fmaxf(fmaf(s.x + sv.x, dv, b[2 * j]), 0.f);
        float oy = fmaxf(fmaf(s.y + sv.y, dv, b[2 * j + 1]), 0.f);
        ((float2*)&As[w][0])[j] = make_float2(ox, oy);
        ((__half2*)hs_out)[(size_t)n * 32 + j] =
            __halves2half2(__float2half(ox), __float2half(oy));
    }
    __syncthreads();

    // wave 0: gemm for the block's 4 nodes, 4 acc/thread (4x W reuse, ILP 4)
    if (tid < 64) {
        float acc[4] = {0.f, 0.f, 0.f, 0.f};
#pragma unroll
        for (int k = 0; k < 64; k += 4) {
            float4 a0 = *(const float4*)&As[0][k];   // wave-uniform broadcasts
            float4 a1 = *(const float4*)&As[1][k];
            float4 a2 = *(const float4*)&As[2][k];
            float4 a3 = *(const float4*)&As[3][k];
            float w0 = W[(k + 0) * 64 + tid];
            float w1 = W[(k + 1) * 64 + tid];
            float w2 = W[(k + 2) * 64 + tid];
            float w3 = W[(k + 3) * 64 + tid];
            acc[0] = fmaf(a0.w, w3, fmaf(a0.z, w2, fmaf(a0.y, w1, fmaf(a0.x, w0, acc[0]))));
            acc[1] = fmaf(a1.w, w3, fmaf(a1.z, w2, fmaf(a1.y, w1, fmaf(a1.x, w0, acc[1]))));
            acc[2] = fmaf(a2.w, w3, fmaf(a2.z, w2, fmaf(a2.y, w1, fmaf(a2.x, w0, acc[2]))));
            acc[3] = fmaf(a3.w, w3, fmaf(a3.z, w2, fmaf(a3.y, w1, fmaf(a3.x, w0, acc[3]))));
        }
#pragma unroll
        for (int i = 0; i < 4; i++) {
            int nn = node0 + i;
            hd_out[(size_t)nn * 64 + tid] = __float2half(acc[i] * dinv[nn]);
        }
    }
}

// ---------------- last: agg(l3) + attention + projection(wave0 4-acc) ----------------

__global__ __launch_bounds__(256) void k_last(const __half2* __restrict__ hd_in,
                                              const float* __restrict__ b,
                                              const float* __restrict__ dinv,
                                              const int* __restrict__ cnt,
                                              const int* __restrict__ cursor,
                                              const unsigned short* __restrict__ csr16,
                                              const __half* __restrict__ hs16,
                                              const float* __restrict__ Wout,
                                              const float* __restrict__ bout,
                                              float* __restrict__ out) {
    __shared__ float As[4][64];
    int tid = threadIdx.x;
    int w = tid >> 6, lane = tid & 63;
    int j = lane & 31, hw = lane >> 5;
    int node0 = blockIdx.x * 4;
    int n = node0 + w;

    float2 s = agg_node(hd_in, cnt, cursor, csr16, n, j, hw);
    if (hw == 0) {
        float dv = dinv[n];
        float2 sv = __half22float2(hd_in[(size_t)n * 32 + j]);
        float ox = fmaxf(fmaf(s.x + sv.x, dv, b[2 * j]), 0.f);
        float oy = fmaxf(fmaf(s.y + sv.y, dv, b[2 * j + 1]), 0.f);
        ((float2*)&As[w][0])[j] = make_float2(ox, oy);
    }
    __builtin_amdgcn_wave_barrier();

    // attention over layers (wave = node; feature = lane)
    float v[N_LAYER], sc[N_LAYER];
#pragma unroll
    for (int l = 0; l < 3; l++) {
        float val = __half2float(hs16[((size_t)l * N_NODES + n) * 64 + lane]);
        v[l]  = val;
        sc[l] = val * val;
    }
    v[3]  = As[w][lane];
    sc[3] = v[3] * v[3];
#pragma unroll
    for (int off = 32; off > 0; off >>= 1) {
#pragma unroll
        for (int l = 0; l < N_LAYER; l++) sc[l] += __shfl_xor(sc[l], off, 64);
    }
    float m = fmaxf(fmaxf(sc[0], sc[1]), fmaxf(sc[2], sc[3]));
    float e[N_LAYER];
    float sum = 0.f;
#pragma unroll
    for (int l = 0; l < N_LAYER; l++) { e[l] = __expf(sc[l] - m); sum += e[l]; }
    float inv = 1.f / sum;
    float bl = 0.f;
#pragma unroll
    for (int l = 0; l < N_LAYER; l++) bl = fmaf(e[l] * inv, v[l], bl);
    As[w][lane] = bl;                     // own-thread address: ordered after read
    __syncthreads();

    // wave 0: projection for the block's 4 nodes, 4 acc/thread
    if (tid < 64 && tid < N_CLASS) {
        float acc[4] = {bout[tid], bout[tid], bout[tid], bout[tid]};
#pragma unroll
        for (int k = 0; k < 64; k += 4) {
            float4 a0 = *(const float4*)&As[0][k];
            float4 a1 = *(const float4*)&As[1][k];
            float4 a2 = *(const float4*)&As[2][k];
            float4 a3 = *(const float4*)&As[3][k];
            float w0 = Wout[(k + 0) * N_CLASS + tid];
            float w1 = Wout[(k + 1) * N_CLASS + tid];
            float w2 = Wout[(k + 2) * N_CLASS + tid];
            float w3 = Wout[(k + 3) * N_CLASS + tid];
            acc[0] = fmaf(a0.w, w3, fmaf(a0.z, w2, fmaf(a0.y, w1, fmaf(a0.x, w0, acc[0]))));
            acc[1] = fmaf(a1.w, w3, fmaf(a1.z, w2, fmaf(a1.y, w1, fmaf(a1.x, w0, acc[1]))));
            acc[2] = fmaf(a2.w, w3, fmaf(a2.z, w2, fmaf(a2.y, w1, fmaf(a2.x, w0, acc[2]))));
            acc[3] = fmaf(a3.w, w3, fmaf(a3.z, w2, fmaf(a3.y, w1, fmaf(a3.x, w0, acc[3]))));
        }
#pragma unroll
        for (int i = 0; i < 4; i++)
            out[(size_t)(node0 + i) * N_CLASS + tid] = acc[i];
    }
}

// ---------------- launch ----------------

extern "C" void kernel_launch(void* const* d_in, const int* in_sizes, int n_in,
                              void* d_out, int out_size, void* d_ws, size_t ws_size,
                              hipStream_t stream) {
    const float* x    = (const float*)d_in[0];
    const float* W0   = (const float*)d_in[1];
    const float* b0   = (const float*)d_in[2];
    const float* Ws   = (const float*)d_in[3];
    const float* bs   = (const float*)d_in[4];
    const float* Wout = (const float*)d_in[5];
    const float* bout = (const float*)d_in[6];
    const int*   ei   = (const int*)d_in[7];
    const int* src = ei;
    const int* dst = ei + N_EDGES;
    float* out = (float*)d_out;

    int*            cnt    = (int*)d_ws;                            // N
    int*            cursor = cnt + N_NODES;                         // N
    unsigned short* csr16  = (unsigned short*)(cursor + N_NODES);   // E ushort
    int*            bktot  = (int*)(csr16 + N_EDGES);               // NBUCK
    int*            bbase  = bktot + NBUCK;                         // NBUCK+1
    int*            bcur   = bbase + NBUCK + 1;                     // NBUCK*BPAD
    float*          dinv   = (float*)(bcur + NBUCK * BPAD);         // N
    __half*         hdA    = (__half*)(dinv + N_NODES);             // N*64
    __half*         hdB    = hdA + (size_t)N_NODES * 64;            // N*64
    __half*         hs16   = hdB + (size_t)N_NODES * 64;            // 3*N*64
    unsigned int*   stag   = (unsigned int*)hs16;                   // E, aliased (build only)

    k_zerob <<<1, 256, 0, stream>>>(bktot);
    k_hist  <<<NBBLK, 256, 0, stream>>>(dst, bktot);
    k_scanb <<<1, 256, 0, stream>>>(bktot, bbase, bcur);
    k_bucket<<<NBBLK, 256, 0, stream>>>(src, dst, bcur, stag);
    k_csr2  <<<NBUCK, 256, 0, stream>>>(stag, bbase, cnt, cursor, dinv, csr16);

    k_gemm0<<<N_NODES / 16, 256, 0, stream>>>(x, W0, dinv, hdA);

    const int NB = N_NODES / 4;   // 12500 blocks x 256 threads, wave = node (agg)

    k_fused<<<NB, 256, 0, stream>>>((const __half2*)hdA, b0, dinv, cnt, cursor, csr16,
                                    Ws + 0 * 64 * 64, hs16 + (size_t)0 * N_NODES * 64, hdB);
    k_fused<<<NB, 256, 0, stream>>>((const __half2*)hdB, bs + 0 * 64, dinv, cnt, cursor, csr16,
                                    Ws + 1 * 64 * 64, hs16 + (size_t)1 * N_NODES * 64, hdA);
    k_fused<<<NB, 256, 0, stream>>>((const __half2*)hdA, bs + 1 * 64, dinv, cnt, cursor, csr16,
                                    Ws + 2 * 64 * 64, hs16 + (size_t)2 * N_NODES * 64, hdB);
    k_last <<<NB, 256, 0, stream>>>((const __half2*)hdB, bs + 2 * 64, dinv, cnt, cursor, csr16,
                                    hs16, Wout, bout, out);
}

// Round 12
// 186.431 us; speedup vs baseline: 1.7205x; 1.1285x over previous
//
#include <hip/hip_runtime.h>
#include <hip/hip_fp16.h>

#define N_NODES 50000
#define N_HID   64
#define N_LAYER 4
#define N_CLASS 40
#define N_EDGES 800000

#define BSHIFT 8
#define BSIZE  256                                      // nodes per bucket
#define NBUCK  ((N_NODES + BSIZE - 1) / BSIZE)          // 196
#define BPAD   16                                      // bucket-cursor stride (64B)
#define EPT    16                                      // edges per thread (bucket pass)
#define BKCHUNK (256 * EPT)                             // 4096 edges per block
#define NBBLK  ((N_EDGES + BKCHUNK - 1) / BKCHUNK)      // 196

#define SCAP  5120                                      // fixed stag window per bucket
                                                        // (mean 4082, sd 64 -> +16 sigma)
#define PBK   (SCAP + 7 * BSIZE)                        // 6912: padded CSR window
#define DUMMY N_NODES                                   // index of zeroed hd row

// ---------------- init: bucket cursors + dummy hd rows ----------------

__global__ void k_zerob(int* __restrict__ bcur, __half* __restrict__ hdA,
                        __half* __restrict__ hdB) {
    int t = threadIdx.x;
    if (t < NBUCK) bcur[t * BPAD] = t * SCAP;
    if (t < 64) {
        hdA[(size_t)N_NODES * 64 + t] = __float2half(0.f);
        hdB[(size_t)N_NODES * 64 + t] = __float2half(0.f);
    }
}

// ---------------- block-binned append of packed (dst<<16)|src into fixed bucket windows ----------------

__global__ void k_bucket(const int* __restrict__ src, const int* __restrict__ dst,
                         int* __restrict__ bcur, unsigned int* __restrict__ stag) {
    __shared__ int lhist[NBUCK];
    __shared__ int gbase[NBUCK];
    int t = threadIdx.x;
    for (int i = t; i < NBUCK; i += 256) lhist[i] = 0;
    __syncthreads();

    int base = blockIdx.x * BKCHUNK;
    unsigned int rec[EPT];
    int br[EPT];
#pragma unroll
    for (int i = 0; i < EPT; i++) {
        int e = base + i * 256 + t;      // coalesced
        if (e < N_EDGES) {
            int d = dst[e], s = src[e];
            int b = d >> BSHIFT;
            int r = atomicAdd(&lhist[b], 1);   // in-block rank within bucket
            rec[i] = ((unsigned int)d << 16) | (unsigned int)s;
            br[i]  = (b << 16) | r;            // r < 4096
        } else {
            br[i] = -1;
        }
    }
    __syncthreads();
    for (int i = t; i < NBUCK; i += 256) {
        int c = lhist[i];
        gbase[i] = c ? atomicAdd(&bcur[i * BPAD], c) : 0;
    }
    __syncthreads();
#pragma unroll
    for (int i = 0; i < EPT; i++) {
        if (br[i] >= 0) {
            int b = br[i] >> 16, r = br[i] & 0xffff;
            stag[gbase[b] + r] = rec[i];
        }
    }
}

// ---------------- per-bucket: LDS count + scan -> padded CSR rows ----------------
// Rows padded to multiples of 8 with DUMMY (zero hd row) -> branch-free agg.

__global__ void k_csr2(const unsigned int* __restrict__ stag, const int* __restrict__ bcur,
                       int* __restrict__ cnt, int* __restrict__ pcurg,
                       float* __restrict__ dinv, unsigned short* __restrict__ csr16) {
    __shared__ int lcnt[BSIZE], ltmp[BSIZE], lcur[BSIZE];
    int b = blockIdx.x, t = threadIdx.x;
    int bstart = b * SCAP;
    int bend   = bcur[b * BPAD];         // post-append cursor = bucket end
    lcnt[t] = 0;
    __syncthreads();
    for (int i = bstart + t; i < bend; i += 256)
        atomicAdd(&lcnt[(stag[i] >> 16) & (BSIZE - 1)], 1);
    __syncthreads();
    int v = lcnt[t];
    int p = (v + 7) & ~7;                // padded row size
    ltmp[t] = p;
    __syncthreads();
    for (int off = 1; off < 256; off <<= 1) {
        int u = (t >= off) ? ltmp[t - off] : 0;
        __syncthreads();
        ltmp[t] += u;
        __syncthreads();
    }
    int pstart = b * PBK + ltmp[t] - p;  // node's padded CSR row start
    lcur[t] = pstart;
    int node = (b << BSHIFT) + t;
    if (node < N_NODES) {
        cnt[node]   = v;
        pcurg[node] = pstart;
        dinv[node]  = rsqrtf((float)(v + 1));
    }
    __syncthreads();
    for (int i = bstart + t; i < bend; i += 256) {
        unsigned int rec = stag[i];
        int pos = atomicAdd(&lcur[(rec >> 16) & (BSIZE - 1)], 1);
        csr16[pos] = (unsigned short)rec;
    }
    for (int i = v; i < p; i++)          // fill pad slots with dummy zero-row
        csr16[pstart + i] = (unsigned short)DUMMY;
}

// ---------------- layer-0 GEMM (tiled, 4 acc/thread): hd = half((x@W0)*dinv) ----------------

__global__ __launch_bounds__(256) void k_gemm0(const float* __restrict__ A,
                                               const float* __restrict__ W,
                                               const float* __restrict__ dinv,
                                               __half* __restrict__ hd) {
    __shared__ float As[16][128];
    int tid = threadIdx.x;
    int j  = tid & 63;
    int nl = tid >> 6;              // 0..3
    int node0 = blockIdx.x * 16;

    const float4* srcp = (const float4*)(A + (size_t)node0 * 128);
    float4* dstp = (float4*)&As[0][0];
    for (int idx = tid; idx < 16 * 128 / 4; idx += 256) dstp[idx] = srcp[idx];
    __syncthreads();

    float acc[4] = {0.f, 0.f, 0.f, 0.f};
#pragma unroll
    for (int k = 0; k < 128; k += 4) {
        float4 a0 = *(const float4*)&As[nl * 4 + 0][k];   // wave-uniform broadcast
        float4 a1 = *(const float4*)&As[nl * 4 + 1][k];
        float4 a2 = *(const float4*)&As[nl * 4 + 2][k];
        float4 a3 = *(const float4*)&As[nl * 4 + 3][k];
        float w0 = W[(k + 0) * 64 + j];
        float w1 = W[(k + 1) * 64 + j];
        float w2 = W[(k + 2) * 64 + j];
        float w3 = W[(k + 3) * 64 + j];
        acc[0] = fmaf(a0.w, w3, fmaf(a0.z, w2, fmaf(a0.y, w1, fmaf(a0.x, w0, acc[0]))));
        acc[1] = fmaf(a1.w, w3, fmaf(a1.z, w2, fmaf(a1.y, w1, fmaf(a1.x, w0, acc[1]))));
        acc[2] = fmaf(a2.w, w3, fmaf(a2.z, w2, fmaf(a2.y, w1, fmaf(a2.x, w0, acc[2]))));
        acc[3] = fmaf(a3.w, w3, fmaf(a3.z, w2, fmaf(a3.y, w1, fmaf(a3.x, w0, acc[3]))));
    }
#pragma unroll
    for (int i = 0; i < 4; i++) {
        int n = node0 + nl * 4 + i;
        hd[(size_t)n * 64 + j] = __float2half(acc[i] * dinv[n]);
    }
}

// ---------------- agg for one node by one wave (branch-free, padded rows) ----------------

__device__ __forceinline__ float2 agg_node(const __half2* __restrict__ hd,
                                           const int* __restrict__ cnt,
                                           const int* __restrict__ pcur,
                                           const unsigned short* __restrict__ csr16,
                                           int n, int j, int hw) {
    int k = pcur[n];
    int iters = (cnt[n] + 7) >> 3;
    float sx = 0.f, sy = 0.f;
#pragma unroll 2
    for (int it = 0; it < iters; ++it, k += 8) {
        int s0 = csr16[k + hw],     s1 = csr16[k + 2 + hw];
        int s2 = csr16[k + 4 + hw], s3 = csr16[k + 6 + hw];
        float2 v0 = __half22float2(hd[(size_t)s0 * 32 + j]);
        float2 v1 = __half22float2(hd[(size_t)s1 * 32 + j]);
        float2 v2 = __half22float2(hd[(size_t)s2 * 32 + j]);
        float2 v3 = __half22float2(hd[(size_t)s3 * 32 + j]);
        sx += (v0.x + v1.x) + (v2.x + v3.x);
        sy += (v0.y + v1.y) + (v2.y + v3.y);
    }
    sx += __shfl_xor(sx, 32);
    sy += __shfl_xor(sy, 32);
    return make_float2(sx, sy);
}

// ---------------- fused: agg(layer l, wave=node) + gemm(layer l+1, wave0 4-acc) ----------------

__global__ __launch_bounds__(256) void k_fused(const __half2* __restrict__ hd_in,
                                               const float* __restrict__ b,
                                               const float* __restrict__ dinv,
                                               const int* __restrict__ cnt,
                                               const int* __restrict__ pcur,
                                               const unsigned short* __restrict__ csr16,
                                               const float* __restrict__ W,
                                               __half* __restrict__ hs_out,
                                               __half* __restrict__ hd_out) {
    __shared__ float As[4][64];
    int tid = threadIdx.x;
    int w = tid >> 6, lane = tid & 63;
    int j = lane & 31, hw = lane >> 5;
    int node0 = blockIdx.x * 4;
    int n = node0 + w;

    float2 s = agg_node(hd_in, cnt, pcur, csr16, n, j, hw);
    if (hw == 0) {
        float dv = dinv[n];
        float2 sv = __half22float2(hd_in[(size_t)n * 32 + j]);   // self row
        float ox = fmaxf(fmaf(s.x + sv.x, dv, b[2 * j]), 0.f);
        float oy = fmaxf(fmaf(s.y + sv.y, dv, b[2 * j + 1]), 0.f);
        ((float2*)&As[w][0])[j] = make_float2(ox, oy);
        ((__half2*)hs_out)[(size_t)n * 32 + j] =
            __halves2half2(__float2half(ox), __float2half(oy));
    }
    __syncthreads();

    // wave 0: gemm for the block's 4 nodes, 4 acc/thread (4x W reuse, ILP 4)
    if (tid < 64) {
        float acc[4] = {0.f, 0.f, 0.f, 0.f};
#pragma unroll
        for (int k = 0; k < 64; k += 4) {
            float4 a0 = *(const float4*)&As[0][k];   // wave-uniform broadcasts
            float4 a1 = *(const float4*)&As[1][k];
            float4 a2 = *(const float4*)&As[2][k];
            float4 a3 = *(const float4*)&As[3][k];
            float w0 = W[(k + 0) * 64 + tid];
            float w1 = W[(k + 1) * 64 + tid];
            float w2 = W[(k + 2) * 64 + tid];
            float w3 = W[(k + 3) * 64 + tid];
            acc[0] = fmaf(a0.w, w3, fmaf(a0.z, w2, fmaf(a0.y, w1, fmaf(a0.x, w0, acc[0]))));
            acc[1] = fmaf(a1.w, w3, fmaf(a1.z, w2, fmaf(a1.y, w1, fmaf(a1.x, w0, acc[1]))));
            acc[2] = fmaf(a2.w, w3, fmaf(a2.z, w2, fmaf(a2.y, w1, fmaf(a2.x, w0, acc[2]))));
            acc[3] = fmaf(a3.w, w3, fmaf(a3.z, w2, fmaf(a3.y, w1, fmaf(a3.x, w0, acc[3]))));
        }
#pragma unroll
        for (int i = 0; i < 4; i++) {
            int nn = node0 + i;
            hd_out[(size_t)nn * 64 + tid] = __float2half(acc[i] * dinv[nn]);
        }
    }
}

// ---------------- last: agg(l3) + attention + projection(wave0 4-acc) ----------------

__global__ __launch_bounds__(256) void k_last(const __half2* __restrict__ hd_in,
                                              const float* __restrict__ b,
                                              const float* __restrict__ dinv,
                                              const int* __restrict__ cnt,
                                              const int* __restrict__ pcur,
                                              const unsigned short* __restrict__ csr16,
                                              const __half* __restrict__ hs16,
                                              const float* __restrict__ Wout,
                                              const float* __restrict__ bout,
                                              float* __restrict__ out) {
    __shared__ float As[4][64];
    int tid = threadIdx.x;
    int w = tid >> 6, lane = tid & 63;
    int j = lane & 31, hw = lane >> 5;
    int node0 = blockIdx.x * 4;
    int n = node0 + w;

    float2 s = agg_node(hd_in, cnt, pcur, csr16, n, j, hw);
    if (hw == 0) {
        float dv = dinv[n];
        float2 sv = __half22float2(hd_in[(size_t)n * 32 + j]);
        float ox = fmaxf(fmaf(s.x + sv.x, dv, b[2 * j]), 0.f);
        float oy = fmaxf(fmaf(s.y + sv.y, dv, b[2 * j + 1]), 0.f);
        ((float2*)&As[w][0])[j] = make_float2(ox, oy);
    }
    __builtin_amdgcn_wave_barrier();

    // attention over layers (wave = node; feature = lane)
    float v[N_LAYER], sc[N_LAYER];
#pragma unroll
    for (int l = 0; l < 3; l++) {
        float val = __half2float(hs16[((size_t)l * N_NODES + n) * 64 + lane]);
        v[l]  = val;
        sc[l] = val * val;
    }
    v[3]  = As[w][lane];
    sc[3] = v[3] * v[3];
#pragma unroll
    for (int off = 32; off > 0; off >>= 1) {
#pragma unroll
        for (int l = 0; l < N_LAYER; l++) sc[l] += __shfl_xor(sc[l], off, 64);
    }
    float m = fmaxf(fmaxf(sc[0], sc[1]), fmaxf(sc[2], sc[3]));
    float e[N_LAYER];
    float sum = 0.f;
#pragma unroll
    for (int l = 0; l < N_LAYER; l++) { e[l] = __expf(sc[l] - m); sum += e[l]; }
    float inv = 1.f / sum;
    float bl = 0.f;
#pragma unroll
    for (int l = 0; l < N_LAYER; l++) bl = fmaf(e[l] * inv, v[l], bl);
    As[w][lane] = bl;                     // own-thread address: ordered after read
    __syncthreads();

    // wave 0: projection for the block's 4 nodes, 4 acc/thread
    if (tid < 64 && tid < N_CLASS) {
        float acc[4] = {bout[tid], bout[tid], bout[tid], bout[tid]};
#pragma unroll
        for (int k = 0; k < 64; k += 4) {
            float4 a0 = *(const float4*)&As[0][k];
            float4 a1 = *(const float4*)&As[1][k];
            float4 a2 = *(const float4*)&As[2][k];
            float4 a3 = *(const float4*)&As[3][k];
            float w0 = Wout[(k + 0) * N_CLASS + tid];
            float w1 = Wout[(k + 1) * N_CLASS + tid];
            float w2 = Wout[(k + 2) * N_CLASS + tid];
            float w3 = Wout[(k + 3) * N_CLASS + tid];
            acc[0] = fmaf(a0.w, w3, fmaf(a0.z, w2, fmaf(a0.y, w1, fmaf(a0.x, w0, acc[0]))));
            acc[1] = fmaf(a1.w, w3, fmaf(a1.z, w2, fmaf(a1.y, w1, fmaf(a1.x, w0, acc[1]))));
            acc[2] = fmaf(a2.w, w3, fmaf(a2.z, w2, fmaf(a2.y, w1, fmaf(a2.x, w0, acc[2]))));
            acc[3] = fmaf(a3.w, w3, fmaf(a3.z, w2, fmaf(a3.y, w1, fmaf(a3.x, w0, acc[3]))));
        }
#pragma unroll
        for (int i = 0; i < 4; i++)
            out[(size_t)(node0 + i) * N_CLASS + tid] = acc[i];
    }
}

// ---------------- launch ----------------

extern "C" void kernel_launch(void* const* d_in, const int* in_sizes, int n_in,
                              void* d_out, int out_size, void* d_ws, size_t ws_size,
                              hipStream_t stream) {
    const float* x    = (const float*)d_in[0];
    const float* W0   = (const float*)d_in[1];
    const float* b0   = (const float*)d_in[2];
    const float* Ws   = (const float*)d_in[3];
    const float* bs   = (const float*)d_in[4];
    const float* Wout = (const float*)d_in[5];
    const float* bout = (const float*)d_in[6];
    const int*   ei   = (const int*)d_in[7];
    const int* src = ei;
    const int* dst = ei + N_EDGES;
    float* out = (float*)d_out;

    int*            cnt   = (int*)d_ws;                             // N
    int*            pcur  = cnt + N_NODES;                          // N
    int*            bcur  = pcur + N_NODES;                         // NBUCK*BPAD
    float*          dinv  = (float*)(bcur + NBUCK * BPAD);          // N
    unsigned short* csr16 = (unsigned short*)(dinv + N_NODES);      // NBUCK*PBK
    __half*         hdA   = (__half*)(csr16 + (size_t)NBUCK * PBK); // (N+1)*64
    __half*         hdB   = hdA + (size_t)(N_NODES + 1) * 64;       // (N+1)*64
    __half*         hs16  = hdB + (size_t)(N_NODES + 1) * 64;       // 3*N*64
    unsigned int*   stag  = (unsigned int*)hs16;                    // NBUCK*SCAP, aliased (build only)

    k_zerob <<<1, 256, 0, stream>>>(bcur, hdA, hdB);
    k_bucket<<<NBBLK, 256, 0, stream>>>(src, dst, bcur, stag);
    k_csr2  <<<NBUCK, 256, 0, stream>>>(stag, bcur, cnt, pcur, dinv, csr16);

    k_gemm0<<<N_NODES / 16, 256, 0, stream>>>(x, W0, dinv, hdA);

    const int NB = N_NODES / 4;   // 12500 blocks x 256 threads, wave = node (agg)

    k_fused<<<NB, 256, 0, stream>>>((const __half2*)hdA, b0, dinv, cnt, pcur, csr16,
                                    Ws + 0 * 64 * 64, hs16 + (size_t)0 * N_NODES * 64, hdB);
    k_fused<<<NB, 256, 0, stream>>>((const __half2*)hdB, bs + 0 * 64, dinv, cnt, pcur, csr16,
                                    Ws + 1 * 64 * 64, hs16 + (size_t)1 * N_NODES * 64, hdA);
    k_fused<<<NB, 256, 0, stream>>>((const __half2*)hdA, bs + 1 * 64, dinv, cnt, pcur, csr16,
                                    Ws + 2 * 64 * 64, hs16 + (size_t)2 * N_NODES * 64, hdB);
    k_last <<<NB, 256, 0, stream>>>((const __half2*)hdB, bs + 2 * 64, dinv, cnt, pcur, csr16,
                                    hs16, Wout, bout, out);
}